// Round 1
// baseline (1609.797 us; speedup 1.0000x reference)
//
#include <hip/hip_runtime.h>

#define NTOK   65536
#define NCODES 1024
#define DIM    128

// ---------------- ee[c] = sum(embed[c,:]^2) in numpy pairwise (8-acc) order ----
__global__ __launch_bounds__(256) void ee_kernel(const float* __restrict__ E,
                                                 float* __restrict__ ee) {
  #pragma clang fp contract(off)
  int c = blockIdx.x * blockDim.x + threadIdx.x;
  if (c >= NCODES) return;
  const float4* r4 = (const float4*)(E + (size_t)c * DIM);
  float v[DIM];
  #pragma unroll
  for (int i = 0; i < 32; ++i) {
    float4 q = r4[i];
    v[4*i] = q.x; v[4*i+1] = q.y; v[4*i+2] = q.z; v[4*i+3] = q.w;
  }
  float r[8];
  #pragma unroll
  for (int j = 0; j < 8; ++j) r[j] = v[j] * v[j];
  #pragma unroll
  for (int i = 1; i < 16; ++i) {
    #pragma unroll
    for (int j = 0; j < 8; ++j) { float s = v[8*i+j] * v[8*i+j]; r[j] = r[j] + s; }
  }
  ee[c] = ((r[0]+r[1])+(r[2]+r[3])) + ((r[4]+r[5])+(r[6]+r[7]));
}

// ---------------- main: argmin over codes + quantized out + segment atomics ----
__global__ __launch_bounds__(256, 3) void vq_main(
    const float* __restrict__ X, const float* __restrict__ E,
    const float* __restrict__ ee, float* __restrict__ out,
    float* __restrict__ counts, float* __restrict__ sums) {
  #pragma clang fp contract(off)
  const int lane  = threadIdx.x & 63;
  const int wave  = __builtin_amdgcn_readfirstlane(threadIdx.x >> 6);
  const int token = blockIdx.x * 64 + lane;

  // x row in registers (static indexing only)
  float x[DIM];
  {
    const float4* xr = (const float4*)(X + (size_t)token * DIM);
    #pragma unroll
    for (int i = 0; i < 32; ++i) {
      float4 v = xr[i];
      x[4*i] = v.x; x[4*i+1] = v.y; x[4*i+2] = v.z; x[4*i+3] = v.w;
    }
  }

  // xx = sum(x^2) in numpy pairwise (8-acc) order
  float xx;
  {
    float r[8];
    #pragma unroll
    for (int j = 0; j < 8; ++j) r[j] = x[j] * x[j];
    #pragma unroll
    for (int i = 1; i < 16; ++i) {
      #pragma unroll
      for (int j = 0; j < 8; ++j) { float s = x[8*i+j] * x[8*i+j]; r[j] = r[j] + s; }
    }
    xx = ((r[0]+r[1])+(r[2]+r[3])) + ((r[4]+r[5])+(r[6]+r[7]));
  }

  // each wave scans its quarter of the codebook; e-row reads are wave-uniform -> s_load
  float best = __builtin_inff();
  int   bidx = 0;
  const int c0 = wave * 256;
  for (int c = c0; c < c0 + 256; ++c) {
    const float* er = E + (size_t)c * DIM;
    float dot = 0.0f;
    #pragma unroll
    for (int k = 0; k < DIM; ++k) dot = __builtin_fmaf(x[k], er[k], dot);
    float dist = (xx + ee[c]) - 2.0f * dot;
    if (dist < best) { best = dist; bidx = c; }  // strict <: first-occurrence ties
  }

  // cross-wave merge (lowest index wins on exact tie, matching np.argmin)
  __shared__ float bv[4][64];
  __shared__ int   bi[4][64];
  bv[wave][lane] = best; bi[wave][lane] = bidx;
  __syncthreads();
  float fb = bv[0][lane]; int fi = bi[0][lane];
  #pragma unroll
  for (int w = 1; w < 4; ++w) {
    float b = bv[w][lane]; int i2 = bi[w][lane];
    if (b < fb || (b == fb && i2 < fi)) { fb = b; fi = i2; }
  }

  const float* eb = E    + (size_t)fi    * DIM;
  float*       op = out  + (size_t)token * DIM;
  float*       sp = sums + (size_t)fi    * DIM;

  // dim-sliced epilogue: literal KB keeps x[] indices compile-time constant
#define EPILOGUE(KB)                                                          \
  {                                                                           \
    _Pragma("unroll")                                                         \
    for (int k4 = 0; k4 < 8; ++k4) {                                          \
      const int kk = (KB) + 4 * k4;                                           \
      float4 q = *(const float4*)(eb + kk);                                   \
      float4 o;                                                               \
      o.x = x[kk+0] + (q.x - x[kk+0]);                                        \
      o.y = x[kk+1] + (q.y - x[kk+1]);                                        \
      o.z = x[kk+2] + (q.z - x[kk+2]);                                        \
      o.w = x[kk+3] + (q.w - x[kk+3]);                                        \
      *(float4*)(op + kk) = o;                                                \
      atomicAdd(sp + kk + 0, x[kk+0]);                                        \
      atomicAdd(sp + kk + 1, x[kk+1]);                                        \
      atomicAdd(sp + kk + 2, x[kk+2]);                                        \
      atomicAdd(sp + kk + 3, x[kk+3]);                                        \
    }                                                                         \
  }

  if      (wave == 0) { EPILOGUE(0)  atomicAdd(counts + fi, 1.0f); }
  else if (wave == 1) { EPILOGUE(32) }
  else if (wave == 2) { EPILOGUE(64) }
  else                { EPILOGUE(96) }
#undef EPILOGUE
}

// ---------------- finalize: EMA + cs + global sum ------------------------------
__global__ __launch_bounds__(1024) void finalize1(
    const float* __restrict__ cluster_size, const float* __restrict__ counts,
    float* __restrict__ out_cs, float* __restrict__ cs_ws) {
  #pragma clang fp contract(off)
  __shared__ float red[1024];
  const int n = threadIdx.x;
  float ncs = 0.99f * cluster_size[n] + 0.01f * counts[n];
  out_cs[n] = ncs;
  red[n] = ncs;
  __syncthreads();
  for (int s = 512; s > 0; s >>= 1) {
    if (n < s) red[n] = red[n] + red[n + s];
    __syncthreads();
  }
  float ntot = red[0];
  cs_ws[n] = (ncs + 1e-5f) / (ntot + 0.01024f) * ntot;
}

__global__ __launch_bounds__(256) void finalize2(
    const float* __restrict__ embed_avg, const float* __restrict__ sums,
    const float* __restrict__ cs_ws, float* __restrict__ out_embed,
    float* __restrict__ out_avg) {
  #pragma clang fp contract(off)
  int i = blockIdx.x * blockDim.x + threadIdx.x;
  float av = 0.99f * embed_avg[i] + 0.01f * sums[i];
  out_avg[i]   = av;
  out_embed[i] = av / cs_ws[i >> 7];
}

extern "C" void kernel_launch(void* const* d_in, const int* in_sizes, int n_in,
                              void* d_out, int out_size, void* d_ws, size_t ws_size,
                              hipStream_t stream) {
  const float* X  = (const float*)d_in[0];
  const float* E  = (const float*)d_in[1];
  const float* CS = (const float*)d_in[2];
  const float* EA = (const float*)d_in[3];
  float* out = (float*)d_out;
  float* ws  = (float*)d_ws;

  float* counts = ws;            // 1024
  float* sums   = ws + 1024;     // 131072
  float* eearr  = ws + 132096;   // 1024
  float* csarr  = ws + 133120;   // 1024

  // zero the atomic accumulators every call (ws is not re-poisoned between replays)
  hipMemsetAsync(d_ws, 0, (1024 + 131072) * sizeof(float), stream);

  ee_kernel<<<NCODES / 256, 256, 0, stream>>>(E, eearr);
  vq_main  <<<NTOK / 64,    256, 0, stream>>>(X, E, eearr, out, counts, sums);
  finalize1<<<1, 1024, 0, stream>>>(CS, counts, out + 8519680, csarr);
  finalize2<<<131072 / 256, 256, 0, stream>>>(EA, sums, csarr,
                                              out + 8388608, out + 8520704);
}

// Round 2
// 1461.593 us; speedup vs baseline: 1.1014x; 1.1014x over previous
//
#include <hip/hip_runtime.h>

#define NTOK   65536
#define NCODES 1024
#define DIM    128
#define BM     128          // tokens per block
#define BN     128          // codes per e-tile
#define NTILE  8            // 1024 / 128

typedef const __attribute__((address_space(1))) char gchar_t;
typedef __attribute__((address_space(3))) char lchar_t;

// ---------------- ee[c] = sum(embed[c,:]^2) in numpy pairwise (8-acc) order ----
__global__ __launch_bounds__(256) void ee_kernel(const float* __restrict__ E,
                                                 float* __restrict__ ee) {
  #pragma clang fp contract(off)
  int c = blockIdx.x * blockDim.x + threadIdx.x;
  if (c >= NCODES) return;
  const float4* r4 = (const float4*)(E + (size_t)c * DIM);
  float v[DIM];
  #pragma unroll
  for (int i = 0; i < 32; ++i) {
    float4 q = r4[i];
    v[4*i] = q.x; v[4*i+1] = q.y; v[4*i+2] = q.z; v[4*i+3] = q.w;
  }
  float r[8];
  #pragma unroll
  for (int j = 0; j < 8; ++j) r[j] = v[j] * v[j];
  #pragma unroll
  for (int i = 1; i < 16; ++i) {
    #pragma unroll
    for (int j = 0; j < 8; ++j) { float s = v[8*i+j] * v[8*i+j]; r[j] = r[j] + s; }
  }
  ee[c] = ((r[0]+r[1])+(r[2]+r[3])) + ((r[4]+r[5])+(r[6]+r[7]));
}

// ---------------- main: register-blocked distance GEMM + argmin + epilogue ----
// 256 threads = (ty 0..15) x (tx 0..15); thread computes 8 tokens x 8 codes.
// E-tile (128 codes x 128 k, 64KB) in LDS, XOR-swizzled: LDS slot (row,k4)
// holds global (row, k4 ^ ((row>>3)&15)); reads undo the swizzle -> 16
// distinct banksets across tx -> conflict-free ds_read_b128.
// X fragments read from global (L1/L2): only 4 distinct addrs/wave.
__global__ __launch_bounds__(256, 2) void vq_main(
    const float* __restrict__ X, const float* __restrict__ E,
    const float* __restrict__ ee, float* __restrict__ out,
    float* __restrict__ counts, float* __restrict__ sums) {
  #pragma clang fp contract(off)
  __shared__ __align__(16) char e_lds[BN * 512];
  __shared__ int idx_s[BM];

  const int tid  = threadIdx.x;
  const int lane = tid & 63;
  const int wv   = tid >> 6;
  const int tx   = tid & 15;
  const int ty   = tid >> 4;
  const long blk = blockIdx.x;

  const float* Xb = X + (size_t)blk * BM * DIM;

  // ---- xx for my 8 tokens (numpy pairwise 8-acc order), from global ----
  float xx[8], best[8];
  int   bidx[8];
  #pragma unroll
  for (int i = 0; i < 8; ++i) {
    const float4* xr = (const float4*)(Xb + (ty * 8 + i) * DIM);
    float r[8];
    {
      float4 A = xr[0], B = xr[1];
      r[0]=A.x*A.x; r[1]=A.y*A.y; r[2]=A.z*A.z; r[3]=A.w*A.w;
      r[4]=B.x*B.x; r[5]=B.y*B.y; r[6]=B.z*B.z; r[7]=B.w*B.w;
    }
    #pragma unroll
    for (int g = 1; g < 16; ++g) {
      float4 A = xr[2*g], B = xr[2*g+1];
      float s0=A.x*A.x, s1=A.y*A.y, s2=A.z*A.z, s3=A.w*A.w;
      float s4=B.x*B.x, s5=B.y*B.y, s6=B.z*B.z, s7=B.w*B.w;
      r[0]=r[0]+s0; r[1]=r[1]+s1; r[2]=r[2]+s2; r[3]=r[3]+s3;
      r[4]=r[4]+s4; r[5]=r[5]+s5; r[6]=r[6]+s6; r[7]=r[7]+s7;
    }
    xx[i]   = ((r[0]+r[1])+(r[2]+r[3])) + ((r[4]+r[5])+(r[6]+r[7]));
    best[i] = __builtin_inff();
    bidx[i] = 0;
  }

  for (int t = 0; t < NTILE; ++t) {
    __syncthreads();   // previous tile fully consumed by all waves
    // ---- stage e-tile t (64KB) via global_load_lds, pre-swizzled source ----
    {
      #pragma unroll
      for (int q = 0; q < 16; ++q) {
        const int row = (wv * 16 + q) * 2 + (lane >> 5);
        const int k4l = lane & 31;
        const int k4g = k4l ^ ((row >> 3) & 15);
        gchar_t* src = (gchar_t*)((const char*)E
                        + ((size_t)(t * BN + row) << 9) + (k4g << 4));
        lchar_t* dst = (lchar_t*)(e_lds + (wv * 16 + q) * 1024);
        __builtin_amdgcn_global_load_lds((const __attribute__((address_space(1))) void*)src,
                                         (__attribute__((address_space(3))) void*)dst,
                                         16, 0, 0);
      }
    }
    asm volatile("s_waitcnt vmcnt(0)" ::: "memory");
    __syncthreads();

    // ---- k-sweep: acc[8][8], sequential-k fmaf chains (bit-matches round 1) --
    float acc[8][8];
    #pragma unroll
    for (int i = 0; i < 8; ++i)
      #pragma unroll
      for (int j = 0; j < 8; ++j) acc[i][j] = 0.0f;

    #pragma unroll 4
    for (int k4 = 0; k4 < 32; ++k4) {
      float4 xf[8], ef[8];
      #pragma unroll
      for (int i = 0; i < 8; ++i)
        xf[i] = *(const float4*)(Xb + (ty * 8 + i) * DIM + k4 * 4);
      #pragma unroll
      for (int j = 0; j < 8; ++j) {
        const int r = tx * 8 + j;             // r>>3 == tx
        ef[j] = *(const float4*)(e_lds + r * 512 + (((k4 ^ tx) & 31) << 4));
      }
      #pragma unroll
      for (int i = 0; i < 8; ++i)
        #pragma unroll
        for (int j = 0; j < 8; ++j) {
          acc[i][j] = __builtin_fmaf(xf[i].x, ef[j].x, acc[i][j]);
          acc[i][j] = __builtin_fmaf(xf[i].y, ef[j].y, acc[i][j]);
          acc[i][j] = __builtin_fmaf(xf[i].z, ef[j].z, acc[i][j]);
          acc[i][j] = __builtin_fmaf(xf[i].w, ef[j].w, acc[i][j]);
        }
    }

    // ---- dist = (xx + ee) - 2*dot ; running argmin (strict <, ascending n) --
    const float4* ee4 = (const float4*)(ee + t * BN + tx * 8);
    float4 eeA = ee4[0], eeB = ee4[1];
    float eev[8] = {eeA.x, eeA.y, eeA.z, eeA.w, eeB.x, eeB.y, eeB.z, eeB.w};
    #pragma unroll
    for (int i = 0; i < 8; ++i)
      #pragma unroll
      for (int j = 0; j < 8; ++j) {
        float d = (xx[i] + eev[j]) - 2.0f * acc[i][j];
        int   n = t * BN + tx * 8 + j;
        if (d < best[i]) { best[i] = d; bidx[i] = n; }
      }
  }

  // ---- cross-tx butterfly reduce (lowest index wins on exact tie) ----------
  #pragma unroll
  for (int i = 0; i < 8; ++i) {
    float b = best[i]; int ix = bidx[i];
    #pragma unroll
    for (int m = 1; m < 16; m <<= 1) {
      float pb = __shfl_xor(b, m, 64);
      int   pi = __shfl_xor(ix, m, 64);
      if (pb < b || (pb == b && pi < ix)) { b = pb; ix = pi; }
    }
    if (tx == 0) idx_s[ty * 8 + i] = ix;
  }
  __syncthreads();

  // ---- epilogue: out = x + (e - x); segment atomics ------------------------
  const int   tt = tid >> 1;
  const int   hf = tid & 1;
  const int   fi = idx_s[tt];
  const float* xrow = Xb + tt * DIM + hf * 64;
  const float* erow = E + (size_t)fi * DIM + hf * 64;
  float*       orow = out + ((size_t)blk * BM + tt) * DIM + hf * 64;
  float*       srow = sums + (size_t)fi * DIM + hf * 64;
  #pragma unroll
  for (int q = 0; q < 16; ++q) {
    float4 xv = *(const float4*)(xrow + q * 4);
    float4 ev = *(const float4*)(erow + q * 4);
    float4 o;
    o.x = xv.x + (ev.x - xv.x);
    o.y = xv.y + (ev.y - xv.y);
    o.z = xv.z + (ev.z - xv.z);
    o.w = xv.w + (ev.w - xv.w);
    *(float4*)(orow + q * 4) = o;
    atomicAdd(srow + q * 4 + 0, xv.x);
    atomicAdd(srow + q * 4 + 1, xv.y);
    atomicAdd(srow + q * 4 + 2, xv.z);
    atomicAdd(srow + q * 4 + 3, xv.w);
  }
  if (hf == 0) atomicAdd(counts + fi, 1.0f);
}

// ---------------- finalize: EMA + cs + global sum ------------------------------
__global__ __launch_bounds__(1024) void finalize1(
    const float* __restrict__ cluster_size, const float* __restrict__ counts,
    float* __restrict__ out_cs, float* __restrict__ cs_ws) {
  #pragma clang fp contract(off)
  __shared__ float red[1024];
  const int n = threadIdx.x;
  float ncs = 0.99f * cluster_size[n] + 0.01f * counts[n];
  out_cs[n] = ncs;
  red[n] = ncs;
  __syncthreads();
  for (int s = 512; s > 0; s >>= 1) {
    if (n < s) red[n] = red[n] + red[n + s];
    __syncthreads();
  }
  float ntot = red[0];
  cs_ws[n] = (ncs + 1e-5f) / (ntot + 0.01024f) * ntot;
}

__global__ __launch_bounds__(256) void finalize2(
    const float* __restrict__ embed_avg, const float* __restrict__ sums,
    const float* __restrict__ cs_ws, float* __restrict__ out_embed,
    float* __restrict__ out_avg) {
  #pragma clang fp contract(off)
  int i = blockIdx.x * blockDim.x + threadIdx.x;
  float av = 0.99f * embed_avg[i] + 0.01f * sums[i];
  out_avg[i]   = av;
  out_embed[i] = av / cs_ws[i >> 7];
}

extern "C" void kernel_launch(void* const* d_in, const int* in_sizes, int n_in,
                              void* d_out, int out_size, void* d_ws, size_t ws_size,
                              hipStream_t stream) {
  const float* X  = (const float*)d_in[0];
  const float* E  = (const float*)d_in[1];
  const float* CS = (const float*)d_in[2];
  const float* EA = (const float*)d_in[3];
  float* out = (float*)d_out;
  float* ws  = (float*)d_ws;

  float* counts = ws;            // 1024
  float* sums   = ws + 1024;     // 131072
  float* eearr  = ws + 132096;   // 1024
  float* csarr  = ws + 133120;   // 1024

  // zero the atomic accumulators every call (ws is not re-poisoned between replays)
  hipMemsetAsync(d_ws, 0, (1024 + 131072) * sizeof(float), stream);

  ee_kernel<<<NCODES / 256, 256, 0, stream>>>(E, eearr);
  vq_main  <<<NTOK / BM,    256, 0, stream>>>(X, E, eearr, out, counts, sums);
  finalize1<<<1, 1024, 0, stream>>>(CS, counts, out + 8519680, csarr);
  finalize2<<<131072 / 256, 256, 0, stream>>>(EA, sums, csarr,
                                              out + 8388608, out + 8520704);
}